// Round 6
// baseline (2871.637 us; speedup 1.0000x reference)
//
#include <hip/hip_runtime.h>

// NOE net sequential scan, round 6.
// vs round 5:
//  (1) exp2 via packed bit-trick (k=a+1.5*2^23 rounding trick + deg-3 poly,
//      exponent spliced with v_lshl_add_u32) -- replaces v_exp_f32 (16cyc)
//      with ~8cyc of packed VALU per exp.
//  (2) single v_rcp for all three sigmoid-dots: rcp(Dz*Dr).
//  (3) NCHUNK=8, WARM=32 (contraction <=0.47/step -> 0.47^32 ~ 3e-11):
//      8 waves/SIMD (VGPR<=64 via launch_bounds) and LESS total work.
// Structure: 8 lanes/row, lane owns 4 units/MLP, DPP butterfly reductions,
// layer-1 weights pre-scaled by -log2e.

typedef float v2 __attribute__((ext_vector_type(2)));

#define T_LEN 2048
#define NCHUNK 8
#define WARM 32

__device__ __forceinline__ v2 mk2(float a, float b) {
  v2 r; r.x = a; r.y = b; return r;
}

template <int CTRL>
__device__ __forceinline__ float dpp_add(float v) {
  return v + __int_as_float(__builtin_amdgcn_update_dpp(
                 0, __float_as_int(v), CTRL, 0xF, 0xF, true));
}

// sum across each aligned 8-lane group; result in all 8 lanes
__device__ __forceinline__ float red8(float v) {
  v = dpp_add<0xB1>(v);   // quad_perm [1,0,3,2] : xor 1
  v = dpp_add<0x4E>(v);   // quad_perm [2,3,0,1] : xor 2
  v = dpp_add<0x141>(v);  // row_half_mirror     : xor 4 within 8
  return v;
}

// packed fast exp2: r = 2^a componentwise, |a| <~ 60, rel err ~6e-4
__device__ __forceinline__ v2 fexp2v(v2 a) {
  const float C = 12582912.0f;  // 1.5 * 2^23
  v2 k = a + C;                  // mantissa now holds round(a)
  v2 km = k - C;                 // = round(a) exactly
  v2 f = a - km;                 // f in [-0.5, 0.5]
  v2 p = ((f * 0.05550411f + 0.24022651f) * f + 0.69314718f) * f + 1.0f;
  v2 r;
  r.x = __uint_as_float(__float_as_uint(p.x) + (__float_as_uint(k.x) << 23));
  r.y = __uint_as_float(__float_as_uint(p.y) + (__float_as_uint(k.y) << 23));
  return r;
}

// pair combine: d = (1+e0)(1+e1), n = w0*(1+e1) + w1*(1+e0)
__device__ __forceinline__ void pairdn(float e0, float e1, float w0, float w1,
                                       float wsum, float& d, float& n) {
  float s = e0 + e1;
  d = fmaf(e0, e1, s + 1.0f);
  n = fmaf(w1, e0, fmaf(w0, e1, wsum));
}

__global__ __launch_bounds__(256, 8) void noenet_scan(
    const float* __restrict__ x,
    const float* __restrict__ l1w, const float* __restrict__ l1b,
    const float* __restrict__ l2w, const float* __restrict__ l2b,
    const float* __restrict__ r1w, const float* __restrict__ r1b,
    const float* __restrict__ r2w, const float* __restrict__ r2b,
    float* __restrict__ y, int B) {
  const unsigned tid = blockIdx.x * blockDim.x + threadIdx.x;
  const unsigned g = tid & 7;
  const unsigned rowc = tid >> 3;
  const unsigned b = rowc & (unsigned)(B - 1);  // B is a power of two (8192)
  const unsigned c = rowc / (unsigned)B;        // chunk index
  if (c >= NCHUNK) return;

  const float NL2E = -1.44269504088896340736f;
  const int ia = (int)g * 4;  // this lane's first hidden unit

  // ---- per-lane weights (pre-scaled by -log2e for layer 1)
  const float4 za0 = *(const float4*)(l1w + ia * 4);
  const float4 za1 = *(const float4*)(l1w + ia * 4 + 4);
  const float4 za2 = *(const float4*)(l1w + ia * 4 + 8);
  const float4 za3 = *(const float4*)(l1w + ia * 4 + 12);
  const v2 zw0A = mk2(za0.x, za1.x) * NL2E, zw0B = mk2(za2.x, za3.x) * NL2E;
  const v2 zw1A = mk2(za0.y, za1.y) * NL2E, zw1B = mk2(za2.y, za3.y) * NL2E;
  const v2 zw2A = mk2(za0.z, za1.z) * NL2E, zw2B = mk2(za2.z, za3.z) * NL2E;
  const v2 zw3A = mk2(za0.w, za1.w) * NL2E, zw3B = mk2(za2.w, za3.w) * NL2E;
  const v2 zbA = mk2(l1b[ia], l1b[ia + 1]) * NL2E;
  const v2 zbB = mk2(l1b[ia + 2], l1b[ia + 3]) * NL2E;

  const float4 ra0 = *(const float4*)(r1w + ia * 4);
  const float4 ra1 = *(const float4*)(r1w + ia * 4 + 4);
  const float4 ra2 = *(const float4*)(r1w + ia * 4 + 8);
  const float4 ra3 = *(const float4*)(r1w + ia * 4 + 12);
  const v2 rw0A = mk2(ra0.x, ra1.x) * NL2E, rw0B = mk2(ra2.x, ra3.x) * NL2E;
  const v2 rw1A = mk2(ra0.y, ra1.y) * NL2E, rw1B = mk2(ra2.y, ra3.y) * NL2E;
  const v2 rw2A = mk2(ra0.z, ra1.z) * NL2E, rw2B = mk2(ra2.z, ra3.z) * NL2E;
  const v2 rw3A = mk2(ra0.w, ra1.w) * NL2E, rw3B = mk2(ra2.w, ra3.w) * NL2E;
  const v2 rbA = mk2(r1b[ia], r1b[ia + 1]) * NL2E;
  const v2 rbB = mk2(r1b[ia + 2], r1b[ia + 3]) * NL2E;

  // layer-2 weights (NOT scaled) + precomputed pair sums
  const float ow0 = l2w[ia], ow1 = l2w[ia + 1];
  const float ow2 = l2w[ia + 2], ow3 = l2w[ia + 3];
  const float ows01 = ow0 + ow1, ows23 = ow2 + ow3;
  const float a0 = r2w[ia], a1 = r2w[ia + 1];
  const float a2 = r2w[ia + 2], a3 = r2w[ia + 3];
  const float as01 = a0 + a1, as23 = a2 + a3;
  const float b0 = r2w[32 + ia], b1 = r2w[32 + ia + 1];
  const float b2 = r2w[32 + ia + 2], b3 = r2w[32 + ia + 3];
  const float bs01 = b0 + b1, bs23 = b2 + b3;

  const float ob  = l2b[0];
  const float hb0 = r2b[0];
  const float hb1 = r2b[1];

  const float* xb = x + (size_t)b * T_LEN;
  float* yb = y + (size_t)b * (T_LEN - 1);

  // ---- chunk bounds (chunk = 256 stored steps)
  const int wstart = (int)c * (T_LEN / NCHUNK);              // first stored t
  const int t0 = (c == 0) ? 0 : wstart - WARM;               // multiple of 32
  const int t_end = (c == NCHUNK - 1) ? (T_LEN - 1)
                                      : wstart + (T_LEN / NCHUNK);
  const int steps = t_end - t0;
  const int nb = steps >> 3;  // full 8-step blocks (tail only in last chunk)

  float h0 = 0.0f, h1 = 0.0f, okeep = 0.0f;

  auto step = [&](float u0, float u1) -> float {
    // pre-activations (scaled by -log2e); h enters last (short chain)
    v2 zaA = zbA + zw0A * u0 + zw1A * u1 + zw2A * h0 + zw3A * h1;
    v2 zaB = zbB + zw0B * u0 + zw1B * u1 + zw2B * h0 + zw3B * h1;
    v2 raA = rbA + rw0A * u0 + rw1A * u1 + rw2A * h0 + rw3A * h1;
    v2 raB = rbB + rw0B * u0 + rw1B * u1 + rw2B * h0 + rw3B * h1;

    const v2 ez1 = fexp2v(zaA);   // e0,e1
    const v2 ez2 = fexp2v(zaB);   // e2,e3
    const v2 er1 = fexp2v(raA);   // f0,f1
    const v2 er2 = fexp2v(raB);   // f2,f3

    // z dot: Nz/Dz over this lane's 4 units
    float dz01, nz01, dz23, nz23;
    pairdn(ez1.x, ez1.y, ow0, ow1, ows01, dz01, nz01);
    pairdn(ez2.x, ez2.y, ow2, ow3, ows23, dz23, nz23);
    const float Dz = dz01 * dz23;
    const float Nz = fmaf(nz01, dz23, nz23 * dz01);

    // recurrent dots: q0,q1 share one denominator Dr
    const float s01 = er1.x + er1.y;
    const float s23 = er2.x + er2.y;
    const float dr01 = fmaf(er1.x, er1.y, s01 + 1.0f);
    const float dr23 = fmaf(er2.x, er2.y, s23 + 1.0f);
    const float n001 = fmaf(a1, er1.x, fmaf(a0, er1.y, as01));
    const float n023 = fmaf(a3, er2.x, fmaf(a2, er2.y, as23));
    const float n101 = fmaf(b1, er1.x, fmaf(b0, er1.y, bs01));
    const float n123 = fmaf(b3, er2.x, fmaf(b2, er2.y, bs23));
    const float Dr = dr01 * dr23;
    const float N0 = fmaf(n001, dr23, n023 * dr01);
    const float N1 = fmaf(n101, dr23, n123 * dr01);

    // single reciprocal for all three dots
    const float rAll = __builtin_amdgcn_rcpf(Dz * Dr);
    const float rDr = Dz * rAll;          // = 1/Dr
    const float opart = (Nz * Dr) * rAll; // = Nz/Dz
    const float p0 = N0 * rDr;
    const float p1 = N1 * rDr;

    const float o   = red8(opart) + ob;
    const float h0n = red8(p0) + hb0;
    const float h1n = red8(p1) + hb1;
    h0 = h0n; h1 = h1n;
    return o;
  };

  float4 cur = *(const float4*)(xb + t0);
  for (int blk = 0; blk < nb; ++blk) {
    const int t = t0 + blk * 8;
    const float4 mid = *(const float4*)(xb + t + 4);
    const float4 nxt = *(const float4*)(xb + t + 8);
    const float u[9] = {cur.x, cur.y, cur.z, cur.w,
                        mid.x, mid.y, mid.z, mid.w, nxt.x};
#pragma unroll
    for (int s = 0; s < 8; ++s) {
      float o = step(u[s], u[s + 1]);
      okeep = (g == (unsigned)s) ? o : okeep;
    }
    if (t >= wstart) yb[t + g] = okeep;  // 8-wide coalesced store
    cur = nxt;
  }
  if (steps & 7) {  // last chunk only: 7 tail steps (t = 2040..2046)
    const int t = t0 + nb * 8;
    const float4 mid = *(const float4*)(xb + t + 4);
    const float u[8] = {cur.x, cur.y, cur.z, cur.w,
                        mid.x, mid.y, mid.z, mid.w};
#pragma unroll
    for (int s = 0; s < 7; ++s) {
      float o = step(u[s], u[s + 1]);
      okeep = (g == (unsigned)s) ? o : okeep;
    }
    if (g < 7) yb[t + g] = okeep;
  }
}

extern "C" void kernel_launch(void* const* d_in, const int* in_sizes, int n_in,
                              void* d_out, int out_size, void* d_ws, size_t ws_size,
                              hipStream_t stream) {
  const float* x   = (const float*)d_in[0];
  const float* l1w = (const float*)d_in[1];
  const float* l1b = (const float*)d_in[2];
  const float* l2w = (const float*)d_in[3];
  const float* l2b = (const float*)d_in[4];
  const float* r1w = (const float*)d_in[5];
  const float* r1b = (const float*)d_in[6];
  const float* r2w = (const float*)d_in[7];
  const float* r2b = (const float*)d_in[8];
  float* y = (float*)d_out;

  const int B = in_sizes[0] / T_LEN;           // 8192
  const long threads = (long)B * 8 * NCHUNK;   // 8 lanes/row x NCHUNK chunks
  const int block = 256;
  const int grid = (int)((threads + block - 1) / block);

  noenet_scan<<<grid, block, 0, stream>>>(x, l1w, l1b, l2w, l2b,
                                          r1w, r1b, r2w, r2b, y, B);
}

// Round 7
// 404.886 us; speedup vs baseline: 7.0925x; 7.0925x over previous
//
#include <hip/hip_runtime.h>

// NOE net sequential scan, round 7.
// = round 6 math (packed bit-trick exp2, one v_rcp per step, NCHUNK=8/WARM=32)
// WITHOUT the forced min-waves launch bound. Round 6's __launch_bounds__(256,8)
// capped the allocator at 32 VGPRs -> all weights spilled to scratch ->
// 8.8 GB/dispatch of HBM traffic and 9x regression. Natural allocation is
// ~52-64 VGPR; at <=64 the HW grants 8 waves/SIMD anyway (occupancy step at 64).
// Structure: 8 lanes/row, lane owns 4 units/MLP, DPP butterfly reductions,
// layer-1 weights pre-scaled by -log2e, time-chunked contractive scan.

typedef float v2 __attribute__((ext_vector_type(2)));

#define T_LEN 2048
#define NCHUNK 8
#define WARM 32

__device__ __forceinline__ v2 mk2(float a, float b) {
  v2 r; r.x = a; r.y = b; return r;
}

template <int CTRL>
__device__ __forceinline__ float dpp_add(float v) {
  return v + __int_as_float(__builtin_amdgcn_update_dpp(
                 0, __float_as_int(v), CTRL, 0xF, 0xF, true));
}

// sum across each aligned 8-lane group; result in all 8 lanes
__device__ __forceinline__ float red8(float v) {
  v = dpp_add<0xB1>(v);   // quad_perm [1,0,3,2] : xor 1
  v = dpp_add<0x4E>(v);   // quad_perm [2,3,0,1] : xor 2
  v = dpp_add<0x141>(v);  // row_half_mirror     : xor 4 within 8
  return v;
}

// packed fast exp2: r = 2^a componentwise, |a| <~ 60, rel err ~6e-4
__device__ __forceinline__ v2 fexp2v(v2 a) {
  const float C = 12582912.0f;  // 1.5 * 2^23
  v2 k = a + C;                  // mantissa now holds round(a)
  v2 km = k - C;                 // = round(a) exactly
  v2 f = a - km;                 // f in [-0.5, 0.5]
  v2 p = ((f * 0.05550411f + 0.24022651f) * f + 0.69314718f) * f + 1.0f;
  v2 r;
  r.x = __uint_as_float(__float_as_uint(p.x) + (__float_as_uint(k.x) << 23));
  r.y = __uint_as_float(__float_as_uint(p.y) + (__float_as_uint(k.y) << 23));
  return r;
}

// pair combine: d = (1+e0)(1+e1), n = w0*(1+e1) + w1*(1+e0)
__device__ __forceinline__ void pairdn(float e0, float e1, float w0, float w1,
                                       float wsum, float& d, float& n) {
  float s = e0 + e1;
  d = fmaf(e0, e1, s + 1.0f);
  n = fmaf(w1, e0, fmaf(w0, e1, wsum));
}

__global__ __launch_bounds__(256) void noenet_scan(
    const float* __restrict__ x,
    const float* __restrict__ l1w, const float* __restrict__ l1b,
    const float* __restrict__ l2w, const float* __restrict__ l2b,
    const float* __restrict__ r1w, const float* __restrict__ r1b,
    const float* __restrict__ r2w, const float* __restrict__ r2b,
    float* __restrict__ y, int B) {
  const unsigned tid = blockIdx.x * blockDim.x + threadIdx.x;
  const unsigned g = tid & 7;
  const unsigned rowc = tid >> 3;
  const unsigned b = rowc & (unsigned)(B - 1);  // B is a power of two (8192)
  const unsigned c = rowc / (unsigned)B;        // chunk index
  if (c >= NCHUNK) return;

  const float NL2E = -1.44269504088896340736f;
  const int ia = (int)g * 4;  // this lane's first hidden unit

  // ---- per-lane weights (pre-scaled by -log2e for layer 1)
  const float4 za0 = *(const float4*)(l1w + ia * 4);
  const float4 za1 = *(const float4*)(l1w + ia * 4 + 4);
  const float4 za2 = *(const float4*)(l1w + ia * 4 + 8);
  const float4 za3 = *(const float4*)(l1w + ia * 4 + 12);
  const v2 zw0A = mk2(za0.x, za1.x) * NL2E, zw0B = mk2(za2.x, za3.x) * NL2E;
  const v2 zw1A = mk2(za0.y, za1.y) * NL2E, zw1B = mk2(za2.y, za3.y) * NL2E;
  const v2 zw2A = mk2(za0.z, za1.z) * NL2E, zw2B = mk2(za2.z, za3.z) * NL2E;
  const v2 zw3A = mk2(za0.w, za1.w) * NL2E, zw3B = mk2(za2.w, za3.w) * NL2E;
  const v2 zbA = mk2(l1b[ia], l1b[ia + 1]) * NL2E;
  const v2 zbB = mk2(l1b[ia + 2], l1b[ia + 3]) * NL2E;

  const float4 ra0 = *(const float4*)(r1w + ia * 4);
  const float4 ra1 = *(const float4*)(r1w + ia * 4 + 4);
  const float4 ra2 = *(const float4*)(r1w + ia * 4 + 8);
  const float4 ra3 = *(const float4*)(r1w + ia * 4 + 12);
  const v2 rw0A = mk2(ra0.x, ra1.x) * NL2E, rw0B = mk2(ra2.x, ra3.x) * NL2E;
  const v2 rw1A = mk2(ra0.y, ra1.y) * NL2E, rw1B = mk2(ra2.y, ra3.y) * NL2E;
  const v2 rw2A = mk2(ra0.z, ra1.z) * NL2E, rw2B = mk2(ra2.z, ra3.z) * NL2E;
  const v2 rw3A = mk2(ra0.w, ra1.w) * NL2E, rw3B = mk2(ra2.w, ra3.w) * NL2E;
  const v2 rbA = mk2(r1b[ia], r1b[ia + 1]) * NL2E;
  const v2 rbB = mk2(r1b[ia + 2], r1b[ia + 3]) * NL2E;

  // layer-2 weights (NOT scaled) + precomputed pair sums
  const float ow0 = l2w[ia], ow1 = l2w[ia + 1];
  const float ow2 = l2w[ia + 2], ow3 = l2w[ia + 3];
  const float ows01 = ow0 + ow1, ows23 = ow2 + ow3;
  const float a0 = r2w[ia], a1 = r2w[ia + 1];
  const float a2 = r2w[ia + 2], a3 = r2w[ia + 3];
  const float as01 = a0 + a1, as23 = a2 + a3;
  const float b0 = r2w[32 + ia], b1 = r2w[32 + ia + 1];
  const float b2 = r2w[32 + ia + 2], b3 = r2w[32 + ia + 3];
  const float bs01 = b0 + b1, bs23 = b2 + b3;

  const float ob  = l2b[0];
  const float hb0 = r2b[0];
  const float hb1 = r2b[1];

  const float* xb = x + (size_t)b * T_LEN;
  float* yb = y + (size_t)b * (T_LEN - 1);

  // ---- chunk bounds (chunk = 256 stored steps)
  const int wstart = (int)c * (T_LEN / NCHUNK);              // first stored t
  const int t0 = (c == 0) ? 0 : wstart - WARM;               // multiple of 32
  const int t_end = (c == NCHUNK - 1) ? (T_LEN - 1)
                                      : wstart + (T_LEN / NCHUNK);
  const int steps = t_end - t0;
  const int nb = steps >> 3;  // full 8-step blocks (tail only in last chunk)

  float h0 = 0.0f, h1 = 0.0f, okeep = 0.0f;

  auto step = [&](float u0, float u1) -> float {
    // pre-activations (scaled by -log2e); h enters last (short chain)
    v2 zaA = zbA + zw0A * u0 + zw1A * u1 + zw2A * h0 + zw3A * h1;
    v2 zaB = zbB + zw0B * u0 + zw1B * u1 + zw2B * h0 + zw3B * h1;
    v2 raA = rbA + rw0A * u0 + rw1A * u1 + rw2A * h0 + rw3A * h1;
    v2 raB = rbB + rw0B * u0 + rw1B * u1 + rw2B * h0 + rw3B * h1;

    const v2 ez1 = fexp2v(zaA);   // e0,e1
    const v2 ez2 = fexp2v(zaB);   // e2,e3
    const v2 er1 = fexp2v(raA);   // f0,f1
    const v2 er2 = fexp2v(raB);   // f2,f3

    // z dot: Nz/Dz over this lane's 4 units
    float dz01, nz01, dz23, nz23;
    pairdn(ez1.x, ez1.y, ow0, ow1, ows01, dz01, nz01);
    pairdn(ez2.x, ez2.y, ow2, ow3, ows23, dz23, nz23);
    const float Dz = dz01 * dz23;
    const float Nz = fmaf(nz01, dz23, nz23 * dz01);

    // recurrent dots: q0,q1 share one denominator Dr
    const float s01 = er1.x + er1.y;
    const float s23 = er2.x + er2.y;
    const float dr01 = fmaf(er1.x, er1.y, s01 + 1.0f);
    const float dr23 = fmaf(er2.x, er2.y, s23 + 1.0f);
    const float n001 = fmaf(a1, er1.x, fmaf(a0, er1.y, as01));
    const float n023 = fmaf(a3, er2.x, fmaf(a2, er2.y, as23));
    const float n101 = fmaf(b1, er1.x, fmaf(b0, er1.y, bs01));
    const float n123 = fmaf(b3, er2.x, fmaf(b2, er2.y, bs23));
    const float Dr = dr01 * dr23;
    const float N0 = fmaf(n001, dr23, n023 * dr01);
    const float N1 = fmaf(n101, dr23, n123 * dr01);

    // single reciprocal for all three dots
    const float rAll = __builtin_amdgcn_rcpf(Dz * Dr);
    const float rDr = Dz * rAll;          // = 1/Dr
    const float opart = (Nz * Dr) * rAll; // = Nz/Dz
    const float p0 = N0 * rDr;
    const float p1 = N1 * rDr;

    const float o   = red8(opart) + ob;
    const float h0n = red8(p0) + hb0;
    const float h1n = red8(p1) + hb1;
    h0 = h0n; h1 = h1n;
    return o;
  };

  float4 cur = *(const float4*)(xb + t0);
  for (int blk = 0; blk < nb; ++blk) {
    const int t = t0 + blk * 8;
    const float4 mid = *(const float4*)(xb + t + 4);
    const float4 nxt = *(const float4*)(xb + t + 8);
    const float u[9] = {cur.x, cur.y, cur.z, cur.w,
                        mid.x, mid.y, mid.z, mid.w, nxt.x};
#pragma unroll
    for (int s = 0; s < 8; ++s) {
      float o = step(u[s], u[s + 1]);
      okeep = (g == (unsigned)s) ? o : okeep;
    }
    if (t >= wstart) yb[t + g] = okeep;  // 8-wide coalesced store
    cur = nxt;
  }
  if (steps & 7) {  // last chunk only: 7 tail steps (t = 2040..2046)
    const int t = t0 + nb * 8;
    const float4 mid = *(const float4*)(xb + t + 4);
    const float u[8] = {cur.x, cur.y, cur.z, cur.w,
                        mid.x, mid.y, mid.z, mid.w};
#pragma unroll
    for (int s = 0; s < 7; ++s) {
      float o = step(u[s], u[s + 1]);
      okeep = (g == (unsigned)s) ? o : okeep;
    }
    if (g < 7) yb[t + g] = okeep;
  }
}

extern "C" void kernel_launch(void* const* d_in, const int* in_sizes, int n_in,
                              void* d_out, int out_size, void* d_ws, size_t ws_size,
                              hipStream_t stream) {
  const float* x   = (const float*)d_in[0];
  const float* l1w = (const float*)d_in[1];
  const float* l1b = (const float*)d_in[2];
  const float* l2w = (const float*)d_in[3];
  const float* l2b = (const float*)d_in[4];
  const float* r1w = (const float*)d_in[5];
  const float* r1b = (const float*)d_in[6];
  const float* r2w = (const float*)d_in[7];
  const float* r2b = (const float*)d_in[8];
  float* y = (float*)d_out;

  const int B = in_sizes[0] / T_LEN;           // 8192
  const long threads = (long)B * 8 * NCHUNK;   // 8 lanes/row x NCHUNK chunks
  const int block = 256;
  const int grid = (int)((threads + block - 1) / block);

  noenet_scan<<<grid, block, 0, stream>>>(x, l1w, l1b, l2w, l2b,
                                          r1w, r1b, r2w, r2b, y, B);
}

// Round 9
// 355.188 us; speedup vs baseline: 8.0848x; 1.1399x over previous
//
#include <hip/hip_runtime.h>

// NOE net sequential scan, round 9.
// = round 3 (best, 318us) with the sigmoid-dot section replaced by a
// swapped-weight batched-reciprocal form, all packable v2 ops, ONE v_rcp:
//   w0/d0 + w1/d1 = hadd({w1,w0} * {d0,d1}) / (d0*d1),   d = 1 + exp2(a)
// pair->quad combine: N = NA*DB + NB*DA, D = DA*DB; q0/q1 share Dr;
// single rcp: R = rcp(Dz*Dr); Nz/Dz = Nz*Dr*R; p = N*(Dz*R).
// Swapped weight pairs are precomputed constants -> no half-swaps, no op_sel.
// Trans per lane-step: 16 -> 9 (8 v_exp + 1 v_rcp), at +~23 cheap VALU.
// Structure unchanged: 8 lanes/row, NCHUNK=4/WARM=64 contractive chunking,
// DPP butterfly reductions, layer-1 weights pre-scaled by -log2e.

typedef float v2 __attribute__((ext_vector_type(2)));

#define T_LEN 2048
#define NCHUNK 4
#define WARM 64

__device__ __forceinline__ v2 mk2(float a, float b) {
  v2 r; r.x = a; r.y = b; return r;
}

template <int CTRL>
__device__ __forceinline__ float dpp_add(float v) {
  return v + __int_as_float(__builtin_amdgcn_update_dpp(
                 0, __float_as_int(v), CTRL, 0xF, 0xF, true));
}

// sum across each aligned 8-lane group; result in all 8 lanes
__device__ __forceinline__ float red8(float v) {
  v = dpp_add<0xB1>(v);   // quad_perm [1,0,3,2] : xor 1
  v = dpp_add<0x4E>(v);   // quad_perm [2,3,0,1] : xor 2
  v = dpp_add<0x141>(v);  // row_half_mirror     : xor 4 within 8
  return v;
}

__global__ __launch_bounds__(256) void noenet_scan(
    const float* __restrict__ x,
    const float* __restrict__ l1w, const float* __restrict__ l1b,
    const float* __restrict__ l2w, const float* __restrict__ l2b,
    const float* __restrict__ r1w, const float* __restrict__ r1b,
    const float* __restrict__ r2w, const float* __restrict__ r2b,
    float* __restrict__ y, int B) {
  const unsigned tid = blockIdx.x * blockDim.x + threadIdx.x;
  const unsigned g = tid & 7;
  const unsigned rowc = tid >> 3;
  const unsigned b = rowc & (unsigned)(B - 1);  // B is a power of two (8192)
  const unsigned c = rowc / (unsigned)B;        // chunk index
  if (c >= NCHUNK) return;

  const float NL2E = -1.44269504088896340736f;
  const int ia = (int)g * 4;  // this lane's first hidden unit

  // ---- per-lane weights: pair A = units ia,ia+1; pair B = units ia+2,ia+3
  // layer-1 rows pre-scaled by -log2e so sigma(x) = 1/(1 + exp2(a))
  const float4 za0 = *(const float4*)(l1w + ia * 4);
  const float4 za1 = *(const float4*)(l1w + ia * 4 + 4);
  const float4 za2 = *(const float4*)(l1w + ia * 4 + 8);
  const float4 za3 = *(const float4*)(l1w + ia * 4 + 12);
  const v2 zw0A = mk2(za0.x, za1.x) * NL2E, zw0B = mk2(za2.x, za3.x) * NL2E;
  const v2 zw1A = mk2(za0.y, za1.y) * NL2E, zw1B = mk2(za2.y, za3.y) * NL2E;
  const v2 zw2A = mk2(za0.z, za1.z) * NL2E, zw2B = mk2(za2.z, za3.z) * NL2E;
  const v2 zw3A = mk2(za0.w, za1.w) * NL2E, zw3B = mk2(za2.w, za3.w) * NL2E;
  const v2 zbA = mk2(l1b[ia], l1b[ia + 1]) * NL2E;
  const v2 zbB = mk2(l1b[ia + 2], l1b[ia + 3]) * NL2E;

  const float4 ra0 = *(const float4*)(r1w + ia * 4);
  const float4 ra1 = *(const float4*)(r1w + ia * 4 + 4);
  const float4 ra2 = *(const float4*)(r1w + ia * 4 + 8);
  const float4 ra3 = *(const float4*)(r1w + ia * 4 + 12);
  const v2 rw0A = mk2(ra0.x, ra1.x) * NL2E, rw0B = mk2(ra2.x, ra3.x) * NL2E;
  const v2 rw1A = mk2(ra0.y, ra1.y) * NL2E, rw1B = mk2(ra2.y, ra3.y) * NL2E;
  const v2 rw2A = mk2(ra0.z, ra1.z) * NL2E, rw2B = mk2(ra2.z, ra3.z) * NL2E;
  const v2 rw3A = mk2(ra0.w, ra1.w) * NL2E, rw3B = mk2(ra2.w, ra3.w) * NL2E;
  const v2 rbA = mk2(r1b[ia], r1b[ia + 1]) * NL2E;
  const v2 rbB = mk2(r1b[ia + 2], r1b[ia + 3]) * NL2E;

  // layer-2 weights, SWAPPED within each pair (only swapped form is needed):
  // hadd(wsw * d) = w0*d1 + w1*d0 = numerator of w0/d0 + w1/d1
  const v2 owAsw = mk2(l2w[ia + 1], l2w[ia]);
  const v2 owBsw = mk2(l2w[ia + 3], l2w[ia + 2]);
  const v2 q0Asw = mk2(r2w[ia + 1], r2w[ia]);
  const v2 q0Bsw = mk2(r2w[ia + 3], r2w[ia + 2]);
  const v2 q1Asw = mk2(r2w[32 + ia + 1], r2w[32 + ia]);
  const v2 q1Bsw = mk2(r2w[32 + ia + 3], r2w[32 + ia + 2]);

  const float ob  = l2b[0];
  const float hb0 = r2b[0];
  const float hb1 = r2b[1];

  const float* xb = x + (size_t)b * T_LEN;
  float* yb = y + (size_t)b * (T_LEN - 1);

  // ---- chunk bounds
  const int wstart = (int)c * (T_LEN / NCHUNK);              // first stored t
  const int t0 = (c == 0) ? 0 : wstart - WARM;               // multiple of 8
  const int t_end = (c == NCHUNK - 1) ? (T_LEN - 1) : wstart + (T_LEN / NCHUNK);
  const int steps = t_end - t0;
  const int nb = steps >> 3;  // full 8-step blocks (tail only in last chunk)

  float h0 = 0.0f, h1 = 0.0f, okeep = 0.0f;

  auto step = [&](float u0, float u1) -> float {
    // pre-activations (scaled by -log2e); h enters last (short chain)
    v2 zaA = zbA + zw0A * u0 + zw1A * u1 + zw2A * h0 + zw3A * h1;
    v2 zaB = zbB + zw0B * u0 + zw1B * u1 + zw2B * h0 + zw3B * h1;
    v2 raA = rbA + rw0A * u0 + rw1A * u1 + rw2A * h0 + rw3A * h1;
    v2 raB = rbB + rw0B * u0 + rw1B * u1 + rw2B * h0 + rw3B * h1;

    v2 ezA, ezB, erA, erB;
    ezA.x = __builtin_amdgcn_exp2f(zaA.x);
    ezA.y = __builtin_amdgcn_exp2f(zaA.y);
    ezB.x = __builtin_amdgcn_exp2f(zaB.x);
    ezB.y = __builtin_amdgcn_exp2f(zaB.y);
    erA.x = __builtin_amdgcn_exp2f(raA.x);
    erA.y = __builtin_amdgcn_exp2f(raA.y);
    erB.x = __builtin_amdgcn_exp2f(raB.x);
    erB.y = __builtin_amdgcn_exp2f(raB.y);

    // denominators 1+e (packed)
    const v2 dzA = ezA + 1.0f;
    const v2 dzB = ezB + 1.0f;
    const v2 drA = erA + 1.0f;
    const v2 drB = erB + 1.0f;

    // z dot: Nz/Dz
    const v2 nz1 = owAsw * dzA;
    const v2 nz2 = owBsw * dzB;
    const float NzA = nz1.x + nz1.y;
    const float NzB = nz2.x + nz2.y;
    const float DzA = dzA.x * dzA.y;
    const float DzB = dzB.x * dzB.y;
    const float Nz = fmaf(NzA, DzB, NzB * DzA);
    const float Dz = DzA * DzB;

    // recurrent dots: q0, q1 share Dr
    const float DrA = drA.x * drA.y;
    const float DrB = drB.x * drB.y;
    const float Dr = DrA * DrB;
    const v2 n01 = q0Asw * drA;
    const v2 n02 = q0Bsw * drB;
    const float N0 = fmaf(n01.x + n01.y, DrB, (n02.x + n02.y) * DrA);
    const v2 n11 = q1Asw * drA;
    const v2 n12 = q1Bsw * drB;
    const float N1 = fmaf(n11.x + n11.y, DrB, (n12.x + n12.y) * DrA);

    // one reciprocal for all three dots
    const float R = __builtin_amdgcn_rcpf(Dz * Dr);
    const float opart = (Nz * Dr) * R;  // = Nz/Dz
    const float rDr = Dz * R;           // = 1/Dr
    const float p0 = N0 * rDr;
    const float p1 = N1 * rDr;

    const float o   = red8(opart) + ob;
    const float h0n = red8(p0) + hb0;
    const float h1n = red8(p1) + hb1;
    h0 = h0n; h1 = h1n;
    return o;
  };

  float4 cur = *(const float4*)(xb + t0);
  for (int blk = 0; blk < nb; ++blk) {
    const int t = t0 + blk * 8;
    const float4 mid = *(const float4*)(xb + t + 4);
    const float4 nxt = *(const float4*)(xb + t + 8);
    const float u[9] = {cur.x, cur.y, cur.z, cur.w,
                        mid.x, mid.y, mid.z, mid.w, nxt.x};
#pragma unroll
    for (int s = 0; s < 8; ++s) {
      float o = step(u[s], u[s + 1]);
      okeep = (g == (unsigned)s) ? o : okeep;
    }
    if (t >= wstart) yb[t + g] = okeep;  // 8-wide coalesced store
    cur = nxt;
  }
  if (steps & 7) {  // last chunk only: 7 tail steps (t = 2040..2046)
    const int t = t0 + nb * 8;
    const float4 mid = *(const float4*)(xb + t + 4);
    const float u[8] = {cur.x, cur.y, cur.z, cur.w,
                        mid.x, mid.y, mid.z, mid.w};
#pragma unroll
    for (int s = 0; s < 7; ++s) {
      float o = step(u[s], u[s + 1]);
      okeep = (g == (unsigned)s) ? o : okeep;
    }
    if (g < 7) yb[t + g] = okeep;
  }
}

extern "C" void kernel_launch(void* const* d_in, const int* in_sizes, int n_in,
                              void* d_out, int out_size, void* d_ws, size_t ws_size,
                              hipStream_t stream) {
  const float* x   = (const float*)d_in[0];
  const float* l1w = (const float*)d_in[1];
  const float* l1b = (const float*)d_in[2];
  const float* l2w = (const float*)d_in[3];
  const float* l2b = (const float*)d_in[4];
  const float* r1w = (const float*)d_in[5];
  const float* r1b = (const float*)d_in[6];
  const float* r2w = (const float*)d_in[7];
  const float* r2b = (const float*)d_in[8];
  float* y = (float*)d_out;

  const int B = in_sizes[0] / T_LEN;           // 8192
  const long threads = (long)B * 8 * NCHUNK;   // 8 lanes/row x NCHUNK chunks
  const int block = 256;
  const int grid = (int)((threads + block - 1) / block);

  noenet_scan<<<grid, block, 0, stream>>>(x, l1w, l1b, l2w, l2b,
                                          r1w, r1b, r2w, r2b, y, B);
}